// Round 2
// baseline (1190.081 us; speedup 1.0000x reference)
//
#include <hip/hip_runtime.h>
#include <cstdint>
#include <cstddef>

// ---------------------------------------------------------------------------
// VirtualNodeGNN: 3x GENConv(softmax aggr) + virtual node + mean pool.
//   - dst-CSR built per call (atomics + scan) -> one-pass online-softmax aggr
//     with the edge encoder FUSED (edgeW staged in LDS; kills the [E,256]
//     buffer and ~300 MB of HBM traffic)
//   - MLP GEMMs via f16 MFMA 16x16x32, 128x128 tiles, XOR-swizzled LDS,
//     through-register staging this round (global_load_lds A/B later)
//   - workspace ~263 MB: h(f32,102M) | t1(f16 [N,512],102M; hn aliases its
//     first half) | agg(51M) | weights/CSR/scan (~6M)
//   - GEMM2 epilogue fuses residual h += conv_out; t1 LayerNorm in place
// ---------------------------------------------------------------------------

typedef _Float16 half8_t __attribute__((ext_vector_type(8)));
typedef _Float16 half4_t __attribute__((ext_vector_type(4)));
typedef float    floatx4 __attribute__((ext_vector_type(4)));

#define DEVINL __device__ __forceinline__

DEVINL float wave_sum(float v) {
#pragma unroll
  for (int m = 32; m; m >>= 1) v += __shfl_xor(v, m, 64);
  return v;
}

// ------------------------------- node encoder ------------------------------
__global__ __launch_bounds__(256) void k_node_enc(
    const float* __restrict__ x, const float* __restrict__ W,
    const float* __restrict__ bias, float* __restrict__ h, int Nr) {
  __shared__ float sW[9 * 256];
  __shared__ float sb[256];
  __shared__ float sx[72];
  const int j = threadIdx.x;
#pragma unroll
  for (int k = 0; k < 9; ++k) sW[k * 256 + j] = W[k * 256 + j];
  sb[j] = bias[j];
  const int row0 = blockIdx.x * 8;
  if (j < 72) {
    int p = row0 * 9 + j;
    sx[j] = (p < Nr * 9) ? x[p] : 0.f;
  }
  __syncthreads();
  for (int r = 0; r < 8; ++r) {
    int row = row0 + r;
    if (row >= Nr) break;
    float acc = sb[j];
#pragma unroll
    for (int k = 0; k < 9; ++k) acc = fmaf(sx[r * 9 + k], sW[k * 256 + j], acc);
    h[(size_t)row * 256 + j] = acc;
  }
}

// ------------------------- counting / scan / CSR ---------------------------
__global__ void k_count(const int* __restrict__ batch, int* __restrict__ counts, int n) {
  int i = blockIdx.x * 256 + threadIdx.x;
  if (i < n) atomicAdd(&counts[batch[i]], 1);
}

__global__ void k_deg(const int* __restrict__ ei, int* __restrict__ deg, int E_) {
  int e = blockIdx.x * 256 + threadIdx.x;
  if (e < E_) atomicAdd(&deg[ei[E_ + e]], 1);  // row 1 of edge_index = dst
}

// inclusive scan of in[0..n) in 1024-chunks; out1[p] = inclusive(p)
__global__ __launch_bounds__(256) void k_scan1(
    const int* __restrict__ in, int* __restrict__ out1, int* __restrict__ bsum, int n) {
  __shared__ int tmp[256];
  const int t = threadIdx.x;
  const int base = blockIdx.x * 1024;
  int v[4];
  int run = 0;
#pragma unroll
  for (int i = 0; i < 4; ++i) {
    int p = base + t * 4 + i;
    int xv = (p < n) ? in[p] : 0;
    run += xv;
    v[i] = run;
  }
  tmp[t] = run;
  __syncthreads();
  for (int off = 1; off < 256; off <<= 1) {
    int u = (t >= off) ? tmp[t - off] : 0;
    __syncthreads();
    tmp[t] += u;
    __syncthreads();
  }
  int excl = tmp[t] - run;
#pragma unroll
  for (int i = 0; i < 4; ++i) {
    int p = base + t * 4 + i;
    if (p < n) out1[p] = v[i] + excl;
  }
  if (t == 255) bsum[blockIdx.x] = tmp[255];
}

__global__ void k_scan2(int* bsum, int nb, int* ptr0) {
  if (threadIdx.x == 0 && blockIdx.x == 0) {
    int run = 0;
    for (int i = 0; i < nb; ++i) { int xv = bsum[i]; bsum[i] = run; run += xv; }
    ptr0[0] = 0;
  }
}

__global__ __launch_bounds__(256) void k_scan3(int* out1, const int* __restrict__ bsum, int n) {
  int add = bsum[blockIdx.x];
  int p0 = blockIdx.x * 1024 + threadIdx.x * 4;
#pragma unroll
  for (int i = 0; i < 4; ++i) {
    int p = p0 + i;
    if (p < n) out1[p] += add;
  }
}

__global__ void k_copy(const int* __restrict__ a, int* __restrict__ b, int n) {
  int i = blockIdx.x * 256 + threadIdx.x;
  if (i < n) b[i] = a[i];
}

__global__ void k_csrfill(const int* __restrict__ ei, int* __restrict__ cursor,
                          int* __restrict__ csr_src, int* __restrict__ csr_eid, int E_) {
  int e = blockIdx.x * 256 + threadIdx.x;
  if (e < E_) {
    int d = ei[E_ + e];
    int pos = atomicAdd(&cursor[d], 1);
    csr_src[pos] = ei[e];
    csr_eid[pos] = e;
  }
}

__global__ void k_invc(const int* __restrict__ counts, float* __restrict__ invc, int Bn) {
  int i = blockIdx.x * 256 + threadIdx.x;
  if (i < Bn) {
    int c = counts[i];
    invc[i] = 1.f / (float)(c > 1 ? c : 1);
  }
}

__global__ void k_vninit(const float* __restrict__ emb, float* __restrict__ vn) {
  vn[(size_t)blockIdx.x * 256 + threadIdx.x] = emb[threadIdx.x];
}

// ------------------------------ LayerNorms ---------------------------------
__global__ __launch_bounds__(256) void k_ln256_f16(
    const float* __restrict__ h, const float* __restrict__ g,
    const float* __restrict__ b, _Float16* __restrict__ out, int Nr) {
  int row = blockIdx.x * 4 + (threadIdx.x >> 6);
  if (row >= Nr) return;
  int lane = threadIdx.x & 63;
  float4 xv = *(const float4*)(h + (size_t)row * 256 + lane * 4);
  float s = wave_sum(xv.x + xv.y + xv.z + xv.w);
  float mu = s * (1.f / 256.f);
  float d0 = xv.x - mu, d1 = xv.y - mu, d2 = xv.z - mu, d3 = xv.w - mu;
  float v = wave_sum(d0 * d0 + d1 * d1 + d2 * d2 + d3 * d3);
  float rstd = rsqrtf(v * (1.f / 256.f) + 1e-5f);
  float4 gv = *(const float4*)(g + lane * 4);
  float4 bv = *(const float4*)(b + lane * 4);
  half4_t o;
  o[0] = (_Float16)fmaxf(d0 * rstd * gv.x + bv.x, 0.f);
  o[1] = (_Float16)fmaxf(d1 * rstd * gv.y + bv.y, 0.f);
  o[2] = (_Float16)fmaxf(d2 * rstd * gv.z + bv.z, 0.f);
  o[3] = (_Float16)fmaxf(d3 * rstd * gv.w + bv.w, 0.f);
  *(half4_t*)(out + (size_t)row * 256 + lane * 4) = o;
}

__global__ __launch_bounds__(256) void k_ln256_f32(
    const float* __restrict__ h, const float* __restrict__ g,
    const float* __restrict__ b, float* __restrict__ out, int Nr) {
  int row = blockIdx.x * 4 + (threadIdx.x >> 6);
  if (row >= Nr) return;
  int lane = threadIdx.x & 63;
  float4 xv = *(const float4*)(h + (size_t)row * 256 + lane * 4);
  float s = wave_sum(xv.x + xv.y + xv.z + xv.w);
  float mu = s * (1.f / 256.f);
  float d0 = xv.x - mu, d1 = xv.y - mu, d2 = xv.z - mu, d3 = xv.w - mu;
  float v = wave_sum(d0 * d0 + d1 * d1 + d2 * d2 + d3 * d3);
  float rstd = rsqrtf(v * (1.f / 256.f) + 1e-5f);
  float4 gv = *(const float4*)(g + lane * 4);
  float4 bv = *(const float4*)(b + lane * 4);
  float4 o;
  o.x = fmaxf(d0 * rstd * gv.x + bv.x, 0.f);
  o.y = fmaxf(d1 * rstd * gv.y + bv.y, 0.f);
  o.z = fmaxf(d2 * rstd * gv.z + bv.z, 0.f);
  o.w = fmaxf(d3 * rstd * gv.w + bv.w, 0.f);
  *(float4*)(out + (size_t)row * 256 + lane * 4) = o;
}

// in-place LN+ReLU on [Nr,512] f16, wave-per-row, 8 elems/lane
__global__ __launch_bounds__(256) void k_ln512_inplace(
    _Float16* __restrict__ t1, const float* __restrict__ g,
    const float* __restrict__ b, int Nr) {
  int row = blockIdx.x * 4 + (threadIdx.x >> 6);
  if (row >= Nr) return;
  int lane = threadIdx.x & 63;
  _Float16* p = t1 + (size_t)row * 512 + lane * 8;
  half8_t x = *(const half8_t*)p;
  float xf[8];
  float s = 0.f;
#pragma unroll
  for (int i = 0; i < 8; ++i) { xf[i] = (float)x[i]; s += xf[i]; }
  s = wave_sum(s);
  float mu = s * (1.f / 512.f);
  float v = 0.f;
#pragma unroll
  for (int i = 0; i < 8; ++i) { float d = xf[i] - mu; v += d * d; }
  v = wave_sum(v);
  float rstd = rsqrtf(v * (1.f / 512.f) + 1e-5f);
  float4 g0 = *(const float4*)(g + lane * 8);
  float4 g1 = *(const float4*)(g + lane * 8 + 4);
  float4 b0 = *(const float4*)(b + lane * 8);
  float4 b1 = *(const float4*)(b + lane * 8 + 4);
  float gg[8] = {g0.x, g0.y, g0.z, g0.w, g1.x, g1.y, g1.z, g1.w};
  float bb[8] = {b0.x, b0.y, b0.z, b0.w, b1.x, b1.y, b1.z, b1.w};
  half8_t o;
#pragma unroll
  for (int i = 0; i < 8; ++i)
    o[i] = (_Float16)fmaxf((xf[i] - mu) * rstd * gg[i] + bb[i], 0.f);
  *(half8_t*)p = o;
}

// --------------------------- softmax aggregation ---------------------------
// wave-per-node online softmax over CSR edges; 4 feats/lane.
// Edge encoder fused: ea[e,j] = eattr[e,:3] . edgeW[:,j] + edgeB[j] (LDS).
__global__ __launch_bounds__(256) void k_aggregate(
    const _Float16* __restrict__ hn, const float* __restrict__ eattr,
    const float* __restrict__ edgeW, const float* __restrict__ edgeB,
    const int* __restrict__ indptr, const int* __restrict__ csr_src,
    const int* __restrict__ csr_eid, const float* __restrict__ tptr,
    _Float16* __restrict__ agg, int Nr) {
  __shared__ float sW[4 * 256];  // [k*256+j] k=0..2 weights, k=3 bias
  const int tj = threadIdx.x;
  sW[tj] = edgeW[tj];
  sW[256 + tj] = edgeW[256 + tj];
  sW[512 + tj] = edgeW[512 + tj];
  sW[768 + tj] = edgeB[tj];
  __syncthreads();  // all threads reach this before any early-out

  int node = blockIdx.x * 4 + (threadIdx.x >> 6);
  if (node >= Nr) return;
  int lane = threadIdx.x & 63;
  float tval = tptr[0];
  int e0 = indptr[node], e1 = indptr[node + 1];
  float M[4], D[4], Nu[4];
#pragma unroll
  for (int i = 0; i < 4; ++i) { M[i] = -1e38f; D[i] = 0.f; Nu[i] = 0.f; }
  for (int s = e0; s < e1; ++s) {
    int srcn = csr_src[s];
    int eid = csr_eid[s];
    float ex0 = eattr[(size_t)eid * 3 + 0];
    float ex1 = eattr[(size_t)eid * 3 + 1];
    float ex2 = eattr[(size_t)eid * 3 + 2];
    half4_t hv = *(const half4_t*)(hn + (size_t)srcn * 256 + lane * 4);
#pragma unroll
    for (int i = 0; i < 4; ++i) {
      int j = lane * 4 + i;
      float eaj = fmaf(ex0, sW[j], fmaf(ex1, sW[256 + j], fmaf(ex2, sW[512 + j], sW[768 + j])));
      float msg = fmaxf((float)hv[i] + eaj, 0.f) + 1e-7f;
      float sc = msg * tval;
      float nM = fmaxf(M[i], sc);
      float sOld = __expf(M[i] - nM);
      float pr = __expf(sc - nM);
      D[i] = D[i] * sOld + pr;
      Nu[i] = Nu[i] * sOld + pr * msg;
      M[i] = nM;
    }
  }
  half4_t hs = *(const half4_t*)(hn + (size_t)node * 256 + lane * 4);
  half4_t res;
#pragma unroll
  for (int i = 0; i < 4; ++i)
    res[i] = (_Float16)(Nu[i] / (D[i] + 1e-16f) + (float)hs[i]);
  *(half4_t*)(agg + (size_t)node * 256 + lane * 4) = res;
}

// ------------------------------- MFMA GEMM ---------------------------------
// C[M,NN] = A[M,K]*B[K,NN] + bias; BT is B^T ([NN,K], k-contiguous).
// 128x128 tile/block (4 waves, each 64x64 via 4x4 MFMA 16x16x32 f16 frags).
// LDS tiles [128 r][64 k] f16, XOR swizzle on 16B chunks: LDS chunk r*8+s
// holds global (r, s^(r&7)) -> frag ds_read_b128 spreads banks (<=2-way).
// Through-register staging (16B loads + ds_write_b128): provably in-bounds.
// MODE 0: store f16. MODE 1: outf[row,col] += v (fused residual into h).
template <int K, int NN, int MODE>
__global__ __launch_bounds__(256) void k_gemm(
    const _Float16* __restrict__ A, const _Float16* __restrict__ BT,
    const float* __restrict__ bias, _Float16* __restrict__ outh,
    float* __restrict__ outf, int M) {
  __shared__ _Float16 ldsA[128 * 64];
  __shared__ _Float16 ldsB[128 * 64];
  const int lane = threadIdx.x & 63;
  const int wv = threadIdx.x >> 6;
  const int m0 = blockIdx.x * 128;
  const int n0 = blockIdx.y * 128;
  const int wm = (wv >> 1) * 64;
  const int wn = (wv & 1) * 64;
  const int q = lane >> 4;
  const int l16 = lane & 15;
  floatx4 acc[4][4] = {};

  for (int kt = 0; kt < K; kt += 64) {
#pragma unroll
    for (int i = 0; i < 4; ++i) {
      int p = (i * 4 + wv) * 64 + lane;  // LDS chunk id 0..1023
      int r = p >> 3;
      int s = p & 7;
      int g = s ^ (r & 7);               // source k-chunk (swizzled)
      int rowA = m0 + r;
      rowA = rowA < M ? rowA : (M - 1);
      half8_t va = *(const half8_t*)(A + (size_t)rowA * K + kt + g * 8);
      half8_t vb = *(const half8_t*)(BT + (size_t)(n0 + r) * K + kt + g * 8);
      *(half8_t*)(ldsA + (size_t)p * 8) = va;
      *(half8_t*)(ldsB + (size_t)p * 8) = vb;
    }
    __syncthreads();
#pragma unroll
    for (int kk = 0; kk < 2; ++kk) {
      half8_t af[4], bf[4];
      const int c8 = kk * 4 + q;
#pragma unroll
      for (int rt = 0; rt < 4; ++rt) {
        int r = wm + rt * 16 + l16;
        af[rt] = *(const half8_t*)(ldsA + (size_t)(r * 8 + (c8 ^ (r & 7))) * 8);
      }
#pragma unroll
      for (int ct = 0; ct < 4; ++ct) {
        int n = wn + ct * 16 + l16;
        bf[ct] = *(const half8_t*)(ldsB + (size_t)(n * 8 + (c8 ^ (n & 7))) * 8);
      }
#pragma unroll
      for (int rt = 0; rt < 4; ++rt)
#pragma unroll
        for (int ct = 0; ct < 4; ++ct)
          acc[rt][ct] = __builtin_amdgcn_mfma_f32_16x16x32_f16(af[rt], bf[ct], acc[rt][ct], 0, 0, 0);
    }
    __syncthreads();
  }

#pragma unroll
  for (int rt = 0; rt < 4; ++rt) {
#pragma unroll
    for (int rr = 0; rr < 4; ++rr) {
      int row = m0 + wm + rt * 16 + q * 4 + rr;  // C/D: col=lane&15, row=q*4+reg
      if (row < M) {
#pragma unroll
        for (int ct = 0; ct < 4; ++ct) {
          int col = n0 + wn + ct * 16 + l16;
          float v = acc[rt][ct][rr] + bias[col];
          if constexpr (MODE == 0)
            outh[(size_t)row * NN + col] = (_Float16)v;
          else
            outf[(size_t)row * NN + col] += v;
        }
      }
    }
  }
}

// ---------------------- weight transpose+convert to f16 --------------------
__global__ __launch_bounds__(256) void k_wcvt(
    const float* __restrict__ W, _Float16* __restrict__ WT, int K_, int N_) {
  int idx = blockIdx.x * 256 + threadIdx.x;
  if (idx < K_ * N_) {
    int k = idx / N_, n = idx - k * N_;
    WT[(size_t)n * K_ + k] = (_Float16)W[idx];
  }
}

// --------------------------- virtual node update ---------------------------
__global__ __launch_bounds__(256) void k_vn(
    float* __restrict__ h, float* __restrict__ vn,
    const int* __restrict__ bptr, const float* __restrict__ invc) {
  int b = blockIdx.x, j = threadIdx.x;
  int n0 = bptr[b], n1 = bptr[b + 1];
  float acc = 0.f;
  for (int n = n0; n < n1; ++n) acc += h[(size_t)n * 256 + j];
  float v = vn[(size_t)b * 256 + j] + acc * invc[b];
  vn[(size_t)b * 256 + j] = v;
  for (int n = n0; n < n1; ++n) h[(size_t)n * 256 + j] += v;
}

__global__ __launch_bounds__(256) void k_pool(
    const float* __restrict__ hnf, const int* __restrict__ bptr,
    const float* __restrict__ invc, float* __restrict__ out) {
  int b = blockIdx.x, j = threadIdx.x;
  int n0 = bptr[b], n1 = bptr[b + 1];
  float acc = 0.f;
  for (int n = n0; n < n1; ++n) acc += hnf[(size_t)n * 256 + j];
  out[(size_t)b * 256 + j] = acc * invc[b];
}

// ---------------------------------------------------------------------------
extern "C" void kernel_launch(void* const* d_in, const int* in_sizes, int n_in,
                              void* d_out, int out_size, void* d_ws, size_t ws_size,
                              hipStream_t stream) {
  const float* x      = (const float*)d_in[0];
  const int*   ei     = (const int*)d_in[1];
  const float* eattr  = (const float*)d_in[2];
  const int*   batch  = (const int*)d_in[3];
  const float* nodeW  = (const float*)d_in[4];
  const float* nodeB  = (const float*)d_in[5];
  const float* edgeW  = (const float*)d_in[6];
  const float* edgeB  = (const float*)d_in[7];
  const float* vnemb  = (const float*)d_in[8];
  const float* lng    = (const float*)d_in[9];
  const float* lnb    = (const float*)d_in[10];
  const float* tparam = (const float*)d_in[11];
  const float* W1     = (const float*)d_in[12];
  const float* b1     = (const float*)d_in[13];
  const float* mlng   = (const float*)d_in[14];
  const float* mlnb   = (const float*)d_in[15];
  const float* W2     = (const float*)d_in[16];
  const float* b2     = (const float*)d_in[17];
  float* out = (float*)d_out;

  const int N = in_sizes[3];         // 100000
  const int E = in_sizes[1] / 2;     // 200000
  const int B = out_size / 256;      // 2048

  // workspace carve-up (~263 MB total; every region fully rewritten per call)
  char* p = (char*)d_ws;
  auto take = [&](size_t bytes) -> char* {
    char* r = p;
    p += (bytes + 255) & ~(size_t)255;
    return r;
  };
  float*     h   = (float*)take((size_t)N * 256 * 4);
  _Float16*  t1  = (_Float16*)take((size_t)N * 512 * 2);  // GEMM1 out [N,512]
  _Float16*  hn  = t1;                 // [N,256] f16 aliases t1's first half:
                                       //   hn live: ln256 -> aggregate; t1 live:
                                       //   gemm1 -> ln512 -> gemm2 (disjoint in time)
  _Float16*  agg = (_Float16*)take((size_t)N * 256 * 2);
  _Float16*  W1T = (_Float16*)take((size_t)3 * 512 * 256 * 2);
  _Float16*  W2T = (_Float16*)take((size_t)3 * 256 * 512 * 2);
  float*     vn  = (float*)take((size_t)B * 256 * 4);
  int*       counts = (int*)take((size_t)B * 4);
  int*       bptr   = (int*)take((size_t)(B + 1) * 4);
  float*     invc   = (float*)take((size_t)B * 4);
  int*       deg    = (int*)take((size_t)N * 4);
  int*       indptr = (int*)take((size_t)(N + 1) * 4);
  int*       cursor = (int*)take((size_t)N * 4);
  int*       csr_src = (int*)take((size_t)E * 4);
  int*       csr_eid = (int*)take((size_t)E * 4);
  int*       bsum    = (int*)take(512 * 4);
  (void)ws_size; (void)n_in;

  hipMemsetAsync(counts, 0, (size_t)B * 4, stream);
  hipMemsetAsync(deg, 0, (size_t)N * 4, stream);

  // node encoder
  k_node_enc<<<(N + 7) / 8, 256, 0, stream>>>(x, nodeW, nodeB, h, N);

  // batch ptr + inv counts
  const int nbB = (B + 1023) / 1024;
  k_count<<<(N + 255) / 256, 256, 0, stream>>>(batch, counts, N);
  k_scan1<<<nbB, 256, 0, stream>>>(counts, bptr + 1, bsum, B);
  k_scan2<<<1, 64, 0, stream>>>(bsum, nbB, bptr);
  k_scan3<<<nbB, 256, 0, stream>>>(bptr + 1, bsum, B);
  k_invc<<<(B + 255) / 256, 256, 0, stream>>>(counts, invc, B);

  // dst-CSR
  const int nbN = (N + 1023) / 1024;
  k_deg<<<(E + 255) / 256, 256, 0, stream>>>(ei, deg, E);
  k_scan1<<<nbN, 256, 0, stream>>>(deg, indptr + 1, bsum, N);
  k_scan2<<<1, 64, 0, stream>>>(bsum, nbN, indptr);
  k_scan3<<<nbN, 256, 0, stream>>>(indptr + 1, bsum, N);
  k_copy<<<(N + 255) / 256, 256, 0, stream>>>(indptr, cursor, N);
  k_csrfill<<<(E + 255) / 256, 256, 0, stream>>>(ei, cursor, csr_src, csr_eid, E);

  // weights -> f16 transposed
  for (int l = 0; l < 3; ++l) {
    k_wcvt<<<512, 256, 0, stream>>>(W1 + (size_t)l * 256 * 512, W1T + (size_t)l * 512 * 256, 256, 512);
    k_wcvt<<<512, 256, 0, stream>>>(W2 + (size_t)l * 512 * 256, W2T + (size_t)l * 256 * 512, 512, 256);
  }
  k_vninit<<<B, 256, 0, stream>>>(vnemb, vn);

  const int lnGrid = (N + 3) / 4;
  const int mTiles = (N + 127) / 128;
  for (int l = 1; l <= 3; ++l) {
    k_ln256_f16<<<lnGrid, 256, 0, stream>>>(h, lng + (size_t)l * 256, lnb + (size_t)l * 256, hn, N);
    k_aggregate<<<lnGrid, 256, 0, stream>>>(hn, eattr, edgeW, edgeB, indptr, csr_src, csr_eid,
                                            tparam + (l - 1), agg, N);
    k_gemm<256, 512, 0><<<dim3(mTiles, 4), 256, 0, stream>>>(
        agg, W1T + (size_t)(l - 1) * 512 * 256, b1 + (size_t)(l - 1) * 512, t1, nullptr, N);
    k_ln512_inplace<<<lnGrid, 256, 0, stream>>>(t1, mlng + (size_t)(l - 1) * 512,
                                                mlnb + (size_t)(l - 1) * 512, N);
    k_gemm<512, 256, 1><<<dim3(mTiles, 2), 256, 0, stream>>>(
        t1, W2T + (size_t)(l - 1) * 256 * 512, b2 + (size_t)(l - 1) * 256, nullptr, h, N);
    k_vn<<<B, 256, 0, stream>>>(h, vn, bptr, invc);
  }

  // final norm + mean pool (hnf f32 [N,256] reuses the dead t1 span)
  float* hnf = (float*)t1;
  k_ln256_f32<<<lnGrid, 256, 0, stream>>>(h, lng, lnb, hnf, N);
  k_pool<<<B, 256, 0, stream>>>(hnf, bptr, invc, out);
}

// Round 3
// 1085.045 us; speedup vs baseline: 1.0968x; 1.0968x over previous
//
#include <hip/hip_runtime.h>
#include <cstdint>
#include <cstddef>

// ---------------------------------------------------------------------------
// VirtualNodeGNN: 3x GENConv(softmax aggr) + virtual node + mean pool.
// R3 changes vs R2 (1190 us):
//   - GEMM k-loop: register-prefetch pipeline (next tile's global loads issue
//     before current tile's MFMAs; vmcnt drain overlaps compute) -> attacks
//     the measured latency-bound profile (MfmaUtil 11%, VALUBusy 16%, 2.9TB/s)
//   - vn chain fused: k_vn (306 MB RMW) -> k_vnsum (102 MB) + "h += vn[batch]"
//     folded into the next layer's LN kernel; final LN emits f16, pool reads f16
// ---------------------------------------------------------------------------

typedef _Float16 half8_t __attribute__((ext_vector_type(8)));
typedef _Float16 half4_t __attribute__((ext_vector_type(4)));
typedef float    floatx4 __attribute__((ext_vector_type(4)));

#define DEVINL __device__ __forceinline__

DEVINL float wave_sum(float v) {
#pragma unroll
  for (int m = 32; m; m >>= 1) v += __shfl_xor(v, m, 64);
  return v;
}

// ------------------------------- node encoder ------------------------------
__global__ __launch_bounds__(256) void k_node_enc(
    const float* __restrict__ x, const float* __restrict__ W,
    const float* __restrict__ bias, float* __restrict__ h, int Nr) {
  __shared__ float sW[9 * 256];
  __shared__ float sb[256];
  __shared__ float sx[72];
  const int j = threadIdx.x;
#pragma unroll
  for (int k = 0; k < 9; ++k) sW[k * 256 + j] = W[k * 256 + j];
  sb[j] = bias[j];
  const int row0 = blockIdx.x * 8;
  if (j < 72) {
    int p = row0 * 9 + j;
    sx[j] = (p < Nr * 9) ? x[p] : 0.f;
  }
  __syncthreads();
  for (int r = 0; r < 8; ++r) {
    int row = row0 + r;
    if (row >= Nr) break;
    float acc = sb[j];
#pragma unroll
    for (int k = 0; k < 9; ++k) acc = fmaf(sx[r * 9 + k], sW[k * 256 + j], acc);
    h[(size_t)row * 256 + j] = acc;
  }
}

// ------------------------- counting / scan / CSR ---------------------------
__global__ void k_count(const int* __restrict__ batch, int* __restrict__ counts, int n) {
  int i = blockIdx.x * 256 + threadIdx.x;
  if (i < n) atomicAdd(&counts[batch[i]], 1);
}

__global__ void k_deg(const int* __restrict__ ei, int* __restrict__ deg, int E_) {
  int e = blockIdx.x * 256 + threadIdx.x;
  if (e < E_) atomicAdd(&deg[ei[E_ + e]], 1);  // row 1 of edge_index = dst
}

__global__ __launch_bounds__(256) void k_scan1(
    const int* __restrict__ in, int* __restrict__ out1, int* __restrict__ bsum, int n) {
  __shared__ int tmp[256];
  const int t = threadIdx.x;
  const int base = blockIdx.x * 1024;
  int v[4];
  int run = 0;
#pragma unroll
  for (int i = 0; i < 4; ++i) {
    int p = base + t * 4 + i;
    int xv = (p < n) ? in[p] : 0;
    run += xv;
    v[i] = run;
  }
  tmp[t] = run;
  __syncthreads();
  for (int off = 1; off < 256; off <<= 1) {
    int u = (t >= off) ? tmp[t - off] : 0;
    __syncthreads();
    tmp[t] += u;
    __syncthreads();
  }
  int excl = tmp[t] - run;
#pragma unroll
  for (int i = 0; i < 4; ++i) {
    int p = base + t * 4 + i;
    if (p < n) out1[p] = v[i] + excl;
  }
  if (t == 255) bsum[blockIdx.x] = tmp[255];
}

__global__ void k_scan2(int* bsum, int nb, int* ptr0) {
  if (threadIdx.x == 0 && blockIdx.x == 0) {
    int run = 0;
    for (int i = 0; i < nb; ++i) { int xv = bsum[i]; bsum[i] = run; run += xv; }
    ptr0[0] = 0;
  }
}

__global__ __launch_bounds__(256) void k_scan3(int* out1, const int* __restrict__ bsum, int n) {
  int add = bsum[blockIdx.x];
  int p0 = blockIdx.x * 1024 + threadIdx.x * 4;
#pragma unroll
  for (int i = 0; i < 4; ++i) {
    int p = p0 + i;
    if (p < n) out1[p] += add;
  }
}

__global__ void k_copy(const int* __restrict__ a, int* __restrict__ b, int n) {
  int i = blockIdx.x * 256 + threadIdx.x;
  if (i < n) b[i] = a[i];
}

__global__ void k_csrfill(const int* __restrict__ ei, int* __restrict__ cursor,
                          int* __restrict__ csr_src, int* __restrict__ csr_eid, int E_) {
  int e = blockIdx.x * 256 + threadIdx.x;
  if (e < E_) {
    int d = ei[E_ + e];
    int pos = atomicAdd(&cursor[d], 1);
    csr_src[pos] = ei[e];
    csr_eid[pos] = e;
  }
}

__global__ void k_invc(const int* __restrict__ counts, float* __restrict__ invc, int Bn) {
  int i = blockIdx.x * 256 + threadIdx.x;
  if (i < Bn) {
    int c = counts[i];
    invc[i] = 1.f / (float)(c > 1 ? c : 1);
  }
}

__global__ void k_vninit(const float* __restrict__ emb, float* __restrict__ vn) {
  vn[(size_t)blockIdx.x * 256 + threadIdx.x] = emb[threadIdx.x];
}

// ------------------------------ LayerNorm ----------------------------------
// wave-per-row (H=256, 4/lane). VN: add vn[batch[row]] first. WH: write h back.
template <int VN, int WH>
__global__ __launch_bounds__(256) void k_ln256(
    const float* __restrict__ h, float* __restrict__ hw,
    const float* __restrict__ vn, const int* __restrict__ batch,
    const float* __restrict__ g, const float* __restrict__ b,
    _Float16* __restrict__ out, int Nr) {
  int row = blockIdx.x * 4 + (threadIdx.x >> 6);
  if (row >= Nr) return;
  int lane = threadIdx.x & 63;
  float4 xv = *(const float4*)(h + (size_t)row * 256 + lane * 4);
  if constexpr (VN) {
    int bb = batch[row];
    float4 vv = *(const float4*)(vn + (size_t)bb * 256 + lane * 4);
    xv.x += vv.x; xv.y += vv.y; xv.z += vv.z; xv.w += vv.w;
    if constexpr (WH) *(float4*)(hw + (size_t)row * 256 + lane * 4) = xv;
  }
  float s = wave_sum(xv.x + xv.y + xv.z + xv.w);
  float mu = s * (1.f / 256.f);
  float d0 = xv.x - mu, d1 = xv.y - mu, d2 = xv.z - mu, d3 = xv.w - mu;
  float v = wave_sum(d0 * d0 + d1 * d1 + d2 * d2 + d3 * d3);
  float rstd = rsqrtf(v * (1.f / 256.f) + 1e-5f);
  float4 gv = *(const float4*)(g + lane * 4);
  float4 bv = *(const float4*)(b + lane * 4);
  half4_t o;
  o[0] = (_Float16)fmaxf(d0 * rstd * gv.x + bv.x, 0.f);
  o[1] = (_Float16)fmaxf(d1 * rstd * gv.y + bv.y, 0.f);
  o[2] = (_Float16)fmaxf(d2 * rstd * gv.z + bv.z, 0.f);
  o[3] = (_Float16)fmaxf(d3 * rstd * gv.w + bv.w, 0.f);
  *(half4_t*)(out + (size_t)row * 256 + lane * 4) = o;
}

// in-place LN+ReLU on [Nr,512] f16, wave-per-row, 8 elems/lane
__global__ __launch_bounds__(256) void k_ln512_inplace(
    _Float16* __restrict__ t1, const float* __restrict__ g,
    const float* __restrict__ b, int Nr) {
  int row = blockIdx.x * 4 + (threadIdx.x >> 6);
  if (row >= Nr) return;
  int lane = threadIdx.x & 63;
  _Float16* p = t1 + (size_t)row * 512 + lane * 8;
  half8_t x = *(const half8_t*)p;
  float xf[8];
  float s = 0.f;
#pragma unroll
  for (int i = 0; i < 8; ++i) { xf[i] = (float)x[i]; s += xf[i]; }
  s = wave_sum(s);
  float mu = s * (1.f / 512.f);
  float v = 0.f;
#pragma unroll
  for (int i = 0; i < 8; ++i) { float d = xf[i] - mu; v += d * d; }
  v = wave_sum(v);
  float rstd = rsqrtf(v * (1.f / 512.f) + 1e-5f);
  float4 g0 = *(const float4*)(g + lane * 8);
  float4 g1 = *(const float4*)(g + lane * 8 + 4);
  float4 b0 = *(const float4*)(b + lane * 8);
  float4 b1 = *(const float4*)(b + lane * 8 + 4);
  float gg[8] = {g0.x, g0.y, g0.z, g0.w, g1.x, g1.y, g1.z, g1.w};
  float bb[8] = {b0.x, b0.y, b0.z, b0.w, b1.x, b1.y, b1.z, b1.w};
  half8_t o;
#pragma unroll
  for (int i = 0; i < 8; ++i)
    o[i] = (_Float16)fmaxf((xf[i] - mu) * rstd * gg[i] + bb[i], 0.f);
  *(half8_t*)p = o;
}

// --------------------------- softmax aggregation ---------------------------
__global__ __launch_bounds__(256) void k_aggregate(
    const _Float16* __restrict__ hn, const float* __restrict__ eattr,
    const float* __restrict__ edgeW, const float* __restrict__ edgeB,
    const int* __restrict__ indptr, const int* __restrict__ csr_src,
    const int* __restrict__ csr_eid, const float* __restrict__ tptr,
    _Float16* __restrict__ agg, int Nr) {
  __shared__ float sW[4 * 256];  // [k*256+j] k=0..2 weights, k=3 bias
  const int tj = threadIdx.x;
  sW[tj] = edgeW[tj];
  sW[256 + tj] = edgeW[256 + tj];
  sW[512 + tj] = edgeW[512 + tj];
  sW[768 + tj] = edgeB[tj];
  __syncthreads();

  int node = blockIdx.x * 4 + (threadIdx.x >> 6);
  if (node >= Nr) return;
  int lane = threadIdx.x & 63;
  float tval = tptr[0];
  int e0 = indptr[node], e1 = indptr[node + 1];
  float M[4], D[4], Nu[4];
#pragma unroll
  for (int i = 0; i < 4; ++i) { M[i] = -1e38f; D[i] = 0.f; Nu[i] = 0.f; }
  for (int s = e0; s < e1; ++s) {
    int srcn = csr_src[s];
    int eid = csr_eid[s];
    float ex0 = eattr[(size_t)eid * 3 + 0];
    float ex1 = eattr[(size_t)eid * 3 + 1];
    float ex2 = eattr[(size_t)eid * 3 + 2];
    half4_t hv = *(const half4_t*)(hn + (size_t)srcn * 256 + lane * 4);
#pragma unroll
    for (int i = 0; i < 4; ++i) {
      int j = lane * 4 + i;
      float eaj = fmaf(ex0, sW[j], fmaf(ex1, sW[256 + j], fmaf(ex2, sW[512 + j], sW[768 + j])));
      float msg = fmaxf((float)hv[i] + eaj, 0.f) + 1e-7f;
      float sc = msg * tval;
      float nM = fmaxf(M[i], sc);
      float sOld = __expf(M[i] - nM);
      float pr = __expf(sc - nM);
      D[i] = D[i] * sOld + pr;
      Nu[i] = Nu[i] * sOld + pr * msg;
      M[i] = nM;
    }
  }
  half4_t hs = *(const half4_t*)(hn + (size_t)node * 256 + lane * 4);
  half4_t res;
#pragma unroll
  for (int i = 0; i < 4; ++i)
    res[i] = (_Float16)(Nu[i] / (D[i] + 1e-16f) + (float)hs[i]);
  *(half4_t*)(agg + (size_t)node * 256 + lane * 4) = res;
}

// ------------------------------- MFMA GEMM ---------------------------------
// C[M,NN] = A[M,K]*B[K,NN] + bias; BT is B^T ([NN,K], k-contiguous).
// 128x128 tile/block, 4 waves each 64x64 (4x4 MFMA 16x16x32 f16 frags).
// XOR-swizzled LDS (16B chunks), register-prefetch pipeline: next k-tile's
// global loads issue BEFORE current tile's MFMAs; vmcnt drain lands at the
// post-compute ds_write, overlapping global latency with compute.
// MODE 0: store f16. MODE 1: outf[row,col] += v (fused residual into h).
template <int K, int NN, int MODE>
__global__ __launch_bounds__(256, 2) void k_gemm(
    const _Float16* __restrict__ A, const _Float16* __restrict__ BT,
    const float* __restrict__ bias, _Float16* __restrict__ outh,
    float* __restrict__ outf, int M) {
  __shared__ _Float16 ldsA[128 * 64];
  __shared__ _Float16 ldsB[128 * 64];
  const int lane = threadIdx.x & 63;
  const int wv = threadIdx.x >> 6;
  const int m0 = blockIdx.x * 128;
  const int n0 = blockIdx.y * 128;
  const int wm = (wv >> 1) * 64;
  const int wn = (wv & 1) * 64;
  const int q = lane >> 4;
  const int l16 = lane & 15;
  floatx4 acc[4][4] = {};

  // per-thread staging addresses (4 A-chunks + 4 B-chunks of 16B)
  size_t offA[4], offB[4];
  int ldsOff[4];
#pragma unroll
  for (int i = 0; i < 4; ++i) {
    int p = (i * 4 + wv) * 64 + lane;  // LDS chunk id 0..1023
    int r = p >> 3;
    int s = p & 7;
    int g = s ^ (r & 7);               // source k-chunk (swizzled)
    int rowA = m0 + r;
    rowA = rowA < M ? rowA : (M - 1);
    offA[i] = (size_t)rowA * K + g * 8;
    offB[i] = (size_t)(n0 + r) * K + g * 8;
    ldsOff[i] = p * 8;
  }
  half8_t ra[4], rb[4];
  auto loadtile = [&](int kt) {
#pragma unroll
    for (int i = 0; i < 4; ++i) {
      ra[i] = *(const half8_t*)(A + offA[i] + kt);
      rb[i] = *(const half8_t*)(BT + offB[i] + kt);
    }
  };
  auto writetile = [&]() {
#pragma unroll
    for (int i = 0; i < 4; ++i) {
      *(half8_t*)(ldsA + ldsOff[i]) = ra[i];
      *(half8_t*)(ldsB + ldsOff[i]) = rb[i];
    }
  };

  loadtile(0);
  writetile();
  for (int kt = 0; kt < K; kt += 64) {
    __syncthreads();                       // LDS tile ready
    if (kt + 64 < K) loadtile(kt + 64);    // issue next tile's global loads
#pragma unroll
    for (int kk = 0; kk < 2; ++kk) {
      half8_t af[4], bf[4];
      const int c8 = kk * 4 + q;
#pragma unroll
      for (int rt = 0; rt < 4; ++rt) {
        int r = wm + rt * 16 + l16;
        af[rt] = *(const half8_t*)(ldsA + (size_t)(r * 8 + (c8 ^ (r & 7))) * 8);
      }
#pragma unroll
      for (int ct = 0; ct < 4; ++ct) {
        int n = wn + ct * 16 + l16;
        bf[ct] = *(const half8_t*)(ldsB + (size_t)(n * 8 + (c8 ^ (n & 7))) * 8);
      }
#pragma unroll
      for (int rt = 0; rt < 4; ++rt)
#pragma unroll
        for (int ct = 0; ct < 4; ++ct)
          acc[rt][ct] = __builtin_amdgcn_mfma_f32_16x16x32_f16(af[rt], bf[ct], acc[rt][ct], 0, 0, 0);
    }
    __syncthreads();                       // all LDS reads done
    if (kt + 64 < K) writetile();          // vmcnt wait here, after compute
  }

#pragma unroll
  for (int rt = 0; rt < 4; ++rt) {
#pragma unroll
    for (int rr = 0; rr < 4; ++rr) {
      int row = m0 + wm + rt * 16 + q * 4 + rr;  // C/D: col=lane&15, row=q*4+reg
      if (row < M) {
#pragma unroll
        for (int ct = 0; ct < 4; ++ct) {
          int col = n0 + wn + ct * 16 + l16;
          float v = acc[rt][ct][rr] + bias[col];
          if constexpr (MODE == 0)
            outh[(size_t)row * NN + col] = (_Float16)v;
          else
            outf[(size_t)row * NN + col] += v;
        }
      }
    }
  }
}

// ---------------------- weight transpose+convert to f16 --------------------
__global__ __launch_bounds__(256) void k_wcvt(
    const float* __restrict__ W, _Float16* __restrict__ WT, int K_, int N_) {
  int idx = blockIdx.x * 256 + threadIdx.x;
  if (idx < K_ * N_) {
    int k = idx / N_, n = idx - k * N_;
    WT[(size_t)n * K_ + k] = (_Float16)W[idx];
  }
}

// --------------------------- virtual node sum ------------------------------
// vn[b] += (sum of h rows in batch b) * invc[b]   (the h+=vn is fused into LN)
__global__ __launch_bounds__(256) void k_vnsum(
    const float* __restrict__ h, float* __restrict__ vn,
    const int* __restrict__ bptr, const float* __restrict__ invc) {
  int b = blockIdx.x, j = threadIdx.x;
  int n0 = bptr[b], n1 = bptr[b + 1];
  float acc = 0.f;
  for (int n = n0; n < n1; ++n) acc += h[(size_t)n * 256 + j];
  vn[(size_t)b * 256 + j] += acc * invc[b];
}

__global__ __launch_bounds__(256) void k_pool_f16(
    const _Float16* __restrict__ hnf, const int* __restrict__ bptr,
    const float* __restrict__ invc, float* __restrict__ out) {
  int b = blockIdx.x, j = threadIdx.x;
  int n0 = bptr[b], n1 = bptr[b + 1];
  float acc = 0.f;
  for (int n = n0; n < n1; ++n) acc += (float)hnf[(size_t)n * 256 + j];
  out[(size_t)b * 256 + j] = acc * invc[b];
}

// ---------------------------------------------------------------------------
extern "C" void kernel_launch(void* const* d_in, const int* in_sizes, int n_in,
                              void* d_out, int out_size, void* d_ws, size_t ws_size,
                              hipStream_t stream) {
  const float* x      = (const float*)d_in[0];
  const int*   ei     = (const int*)d_in[1];
  const float* eattr  = (const float*)d_in[2];
  const int*   batch  = (const int*)d_in[3];
  const float* nodeW  = (const float*)d_in[4];
  const float* nodeB  = (const float*)d_in[5];
  const float* edgeW  = (const float*)d_in[6];
  const float* edgeB  = (const float*)d_in[7];
  const float* vnemb  = (const float*)d_in[8];
  const float* lng    = (const float*)d_in[9];
  const float* lnb    = (const float*)d_in[10];
  const float* tparam = (const float*)d_in[11];
  const float* W1     = (const float*)d_in[12];
  const float* b1     = (const float*)d_in[13];
  const float* mlng   = (const float*)d_in[14];
  const float* mlnb   = (const float*)d_in[15];
  const float* W2     = (const float*)d_in[16];
  const float* b2     = (const float*)d_in[17];
  float* out = (float*)d_out;

  const int N = in_sizes[3];         // 100000
  const int E = in_sizes[1] / 2;     // 200000
  const int B = out_size / 256;      // 2048

  char* p = (char*)d_ws;
  auto take = [&](size_t bytes) -> char* {
    char* r = p;
    p += (bytes + 255) & ~(size_t)255;
    return r;
  };
  float*     h   = (float*)take((size_t)N * 256 * 4);
  _Float16*  t1  = (_Float16*)take((size_t)N * 512 * 2);  // GEMM1 out [N,512]
  _Float16*  hn  = t1;                 // [N,256] f16 aliases t1 (disjoint lifetimes)
  _Float16*  agg = (_Float16*)take((size_t)N * 256 * 2);
  _Float16*  W1T = (_Float16*)take((size_t)3 * 512 * 256 * 2);
  _Float16*  W2T = (_Float16*)take((size_t)3 * 256 * 512 * 2);
  float*     vn  = (float*)take((size_t)B * 256 * 4);
  int*       counts = (int*)take((size_t)B * 4);
  int*       bptr   = (int*)take((size_t)(B + 1) * 4);
  float*     invc   = (float*)take((size_t)B * 4);
  int*       deg    = (int*)take((size_t)N * 4);
  int*       indptr = (int*)take((size_t)(N + 1) * 4);
  int*       cursor = (int*)take((size_t)N * 4);
  int*       csr_src = (int*)take((size_t)E * 4);
  int*       csr_eid = (int*)take((size_t)E * 4);
  int*       bsum    = (int*)take(512 * 4);
  (void)ws_size; (void)n_in;

  hipMemsetAsync(counts, 0, (size_t)B * 4, stream);
  hipMemsetAsync(deg, 0, (size_t)N * 4, stream);

  k_node_enc<<<(N + 7) / 8, 256, 0, stream>>>(x, nodeW, nodeB, h, N);

  const int nbB = (B + 1023) / 1024;
  k_count<<<(N + 255) / 256, 256, 0, stream>>>(batch, counts, N);
  k_scan1<<<nbB, 256, 0, stream>>>(counts, bptr + 1, bsum, B);
  k_scan2<<<1, 64, 0, stream>>>(bsum, nbB, bptr);
  k_scan3<<<nbB, 256, 0, stream>>>(bptr + 1, bsum, B);
  k_invc<<<(B + 255) / 256, 256, 0, stream>>>(counts, invc, B);

  const int nbN = (N + 1023) / 1024;
  k_deg<<<(E + 255) / 256, 256, 0, stream>>>(ei, deg, E);
  k_scan1<<<nbN, 256, 0, stream>>>(deg, indptr + 1, bsum, N);
  k_scan2<<<1, 64, 0, stream>>>(bsum, nbN, indptr);
  k_scan3<<<nbN, 256, 0, stream>>>(indptr + 1, bsum, N);
  k_copy<<<(N + 255) / 256, 256, 0, stream>>>(indptr, cursor, N);
  k_csrfill<<<(E + 255) / 256, 256, 0, stream>>>(ei, cursor, csr_src, csr_eid, E);

  for (int l = 0; l < 3; ++l) {
    k_wcvt<<<512, 256, 0, stream>>>(W1 + (size_t)l * 256 * 512, W1T + (size_t)l * 512 * 256, 256, 512);
    k_wcvt<<<512, 256, 0, stream>>>(W2 + (size_t)l * 512 * 256, W2T + (size_t)l * 256 * 512, 512, 256);
  }
  k_vninit<<<B, 256, 0, stream>>>(vnemb, vn);

  const int lnGrid = (N + 3) / 4;
  const int mTiles = (N + 127) / 128;
  for (int l = 1; l <= 3; ++l) {
    if (l == 1)  // layer 1: no pending vn add
      k_ln256<0, 0><<<lnGrid, 256, 0, stream>>>(
          h, nullptr, nullptr, nullptr, lng + (size_t)l * 256, lnb + (size_t)l * 256, hn, N);
    else         // layers 2,3: h += vn[batch] fused, h written back
      k_ln256<1, 1><<<lnGrid, 256, 0, stream>>>(
          h, h, vn, batch, lng + (size_t)l * 256, lnb + (size_t)l * 256, hn, N);
    k_aggregate<<<lnGrid, 256, 0, stream>>>(hn, eattr, edgeW, edgeB, indptr, csr_src, csr_eid,
                                            tparam + (l - 1), agg, N);
    k_gemm<256, 512, 0><<<dim3(mTiles, 4), 256, 0, stream>>>(
        agg, W1T + (size_t)(l - 1) * 512 * 256, b1 + (size_t)(l - 1) * 512, t1, nullptr, N);
    k_ln512_inplace<<<lnGrid, 256, 0, stream>>>(t1, mlng + (size_t)(l - 1) * 512,
                                                mlnb + (size_t)(l - 1) * 512, N);
    k_gemm<512, 256, 1><<<dim3(mTiles, 2), 256, 0, stream>>>(
        t1, W2T + (size_t)(l - 1) * 256 * 512, b2 + (size_t)(l - 1) * 256, nullptr, h, N);
    k_vnsum<<<B, 256, 0, stream>>>(h, vn, bptr, invc);
  }

  // final: h += vn[batch] fused into LN (h not needed after), f16 out, f16 pool
  k_ln256<1, 0><<<lnGrid, 256, 0, stream>>>(h, nullptr, vn, batch, lng, lnb, hn, N);
  k_pool_f16<<<B, 256, 0, stream>>>(hn, bptr, invc, out);
}